// Round 6
// baseline (557.620 us; speedup 1.0000x reference)
//
#include <hip/hip_runtime.h>
#include <stdint.h>

#define EPSF 1e-5f
#define NEG_INF (-1e30f)

typedef float f32x4 __attribute__((ext_vector_type(4)));
typedef __bf16 bf16x8 __attribute__((ext_vector_type(8)));
typedef unsigned short u16x8 __attribute__((ext_vector_type(8)));
typedef _Float16 h16;
typedef _Float16 h16x8 __attribute__((ext_vector_type(8)));

typedef __attribute__((address_space(3))) unsigned char* as3_ptr;
typedef const __attribute__((address_space(1))) unsigned char* as1_ptr;

__device__ __forceinline__ void async16(const void* g, void* l) {
  __builtin_amdgcn_global_load_lds((as1_ptr)g, (as3_ptr)l, 16, 0, 0);
}

__device__ __forceinline__ unsigned short f2bf(float f) {
  union { float f; unsigned int u; } v; v.f = f;
  unsigned int r = v.u + 0x7FFFu + ((v.u >> 16) & 1u);
  return (unsigned short)(r >> 16);
}
__device__ __forceinline__ unsigned short f2bf_fast(float f) {
  union { float f; unsigned int u; } v; v.f = f;
  return (unsigned short)((v.u + 0x8000u) >> 16);
}

// ---------------- T0: generic 32x32 transpose
__global__ __launch_bounds__(256) void transpose_k(const float* __restrict__ src,
                                                   float* __restrict__ dst, int R, int C) {
  __shared__ float tl[32][33];
  int tx = threadIdx.x & 31, ty = threadIdx.x >> 5;
  int c0 = blockIdx.x * 32, r0 = blockIdx.y * 32;
#pragma unroll
  for (int i = 0; i < 4; i++)
    tl[ty + i * 8][tx] = src[(size_t)(r0 + ty + i * 8) * C + c0 + tx];
  __syncthreads();
#pragma unroll
  for (int i = 0; i < 4; i++)
    dst[(size_t)(c0 + ty + i * 8) * R + r0 + tx] = tl[tx][ty + i * 8];
}

// ---------------- A1: QKV projection
__global__ __launch_bounds__(256) void qkv_k(const float* __restrict__ xT,
    const float* __restrict__ Wq, const float* __restrict__ bq,
    const float* __restrict__ Wk, const float* __restrict__ bk,
    const float* __restrict__ Wv, const float* __restrict__ bv,
    float* __restrict__ Q, float* __restrict__ Kq, float* __restrict__ Vq) {
  __shared__ float xs[64 * 33];
  __shared__ float wq[32 * 33], wk[32 * 33], wvs[32 * 33];
  __shared__ float bqs[32], bks[32], bvs[32];
  int tid = threadIdx.x;
  int a = blockIdx.x;
  int tbase = blockIdx.y * 256;
#pragma unroll
  for (int i = 0; i < 4; i++) {
    int e = i * 256 + tid; int r = e >> 5, c = e & 31;
    wq[r * 33 + c] = Wq[e]; wk[r * 33 + c] = Wk[e]; wvs[r * 33 + c] = Wv[e];
  }
  if (tid < 32) { bqs[tid] = bq[tid]; bks[tid] = bk[tid]; bvs[tid] = bv[tid]; }
  int tl = tid & 63, rg = tid >> 6;
  for (int ch = 0; ch < 4; ch++) {
    __syncthreads();
#pragma unroll
    for (int i = 0; i < 8; i++) {
      int e = i * 256 + tid; int r = e >> 5, c = e & 31;
      xs[r * 33 + c] = xT[(size_t)a * 16384 + (size_t)(tbase + ch * 64) * 32 + e];
    }
    __syncthreads();
    float qa[8], ka[8], va[8];
#pragma unroll
    for (int r8 = 0; r8 < 8; r8++) {
      int r = rg * 8 + r8; qa[r8] = bqs[r]; ka[r8] = bks[r]; va[r8] = bvs[r];
    }
    for (int c = 0; c < 32; c++) {
      float xv = xs[tl * 33 + c];
#pragma unroll
      for (int r8 = 0; r8 < 8; r8++) {
        int r = rg * 8 + r8;
        qa[r8] += xv * wq[r * 33 + c];
        ka[r8] += xv * wk[r * 33 + c];
        va[r8] += xv * wvs[r * 33 + c];
      }
    }
    int t = tbase + ch * 64 + tl;
#pragma unroll
    for (int r8 = 0; r8 < 8; r8++) {
      int r = rg * 8 + r8;
      size_t o = (size_t)a * 16384 + (size_t)r * 512 + t;
      Q[o] = qa[r8]; Kq[o] = ka[r8]; Vq[o] = va[r8];
    }
  }
}

// ---------------- A2+A3 merged: rank-based top-U + attention core.
__global__ __launch_bounds__(512) void topattn_k(const float* __restrict__ Q,
    const float* __restrict__ Kq, const float* __restrict__ Vq,
    const int* __restrict__ idxs, float* __restrict__ Ctx, int U) {
  __shared__ float Ks[2048];
  __shared__ float Vs[2048];
  __shared__ float Ml[512];
  __shared__ int mt[64];
  __shared__ float Qr[64][4];
  __shared__ float upd[64][4];
  int bh = blockIdx.x;
  int tid = threadIdx.x, lane = tid & 63, wv = tid >> 6;
  size_t base = (size_t)bh * 2048;
#pragma unroll
  for (int i = 0; i < 4; i++) {
    Ks[i * 512 + tid] = Kq[base + i * 512 + tid];
    Vs[i * 512 + tid] = Vq[base + i * 512 + tid];
  }
  float q0 = Q[base + tid], q1 = Q[base + 512 + tid];
  float q2 = Q[base + 1024 + tid], q3 = Q[base + 1536 + tid];
  __syncthreads();
  float mx = NEG_INF, sm = 0.f;
  for (int u = 0; u < U; u++) {
    int it = idxs[tid * U + u];
    it = min(max(it, 0), 511);
    float s = q0 * Ks[it] + q1 * Ks[512 + it] + q2 * Ks[1024 + it] + q3 * Ks[1536 + it];
    mx = fmaxf(mx, s); sm += s;
  }
  Ml[tid] = mx - sm * (1.f / 512.f);
  __syncthreads();
  float mi = Ml[tid];
  int rank = 0;
  for (int j0 = 0; j0 < 512; j0 += 4) {
    float4 m4 = *(const float4*)(Ml + j0);
    rank += (m4.x > mi) || (m4.x == mi && (j0 + 0) < tid);
    rank += (m4.y > mi) || (m4.y == mi && (j0 + 1) < tid);
    rank += (m4.z > mi) || (m4.z == mi && (j0 + 2) < tid);
    rank += (m4.w > mi) || (m4.w == mi && (j0 + 3) < tid);
  }
  if (rank < U) mt[rank] = tid;
  __syncthreads();
  if (tid < 4 * U) { int u = tid >> 2, d = tid & 3; Qr[u][d] = Q[base + d * 512 + mt[u]]; }
  __syncthreads();
  for (int u = wv; u < U; u += 8) {
    int mrow = mt[u];
    float p0q = Qr[u][0], p1q = Qr[u][1], p2q = Qr[u][2], p3q = Qr[u][3];
    float sv[8]; float lmax = NEG_INF;
#pragma unroll
    for (int jj = 0; jj < 8; jj++) {
      int k = jj * 64 + lane;
      float s = NEG_INF;
      if (k <= mrow)
        s = 0.5f * (p0q * Ks[k] + p1q * Ks[512 + k] + p2q * Ks[1024 + k] + p3q * Ks[1536 + k]);
      sv[jj] = s; lmax = fmaxf(lmax, s);
    }
#pragma unroll
    for (int off = 32; off; off >>= 1) lmax = fmaxf(lmax, __shfl_xor(lmax, off));
    float ls = 0.f, p0 = 0.f, p1 = 0.f, p2 = 0.f, p3 = 0.f;
#pragma unroll
    for (int jj = 0; jj < 8; jj++) {
      int k = jj * 64 + lane;
      if (k <= mrow) {
        float p = __expf(sv[jj] - lmax);
        ls += p; p0 += p * Vs[k]; p1 += p * Vs[512 + k];
        p2 += p * Vs[1024 + k]; p3 += p * Vs[1536 + k];
      }
    }
#pragma unroll
    for (int off = 32; off; off >>= 1) {
      ls += __shfl_xor(ls, off); p0 += __shfl_xor(p0, off); p1 += __shfl_xor(p1, off);
      p2 += __shfl_xor(p2, off); p3 += __shfl_xor(p3, off);
    }
    if (lane == 0) {
      float inv = 1.f / ls;
      upd[u][0] = p0 * inv; upd[u][1] = p1 * inv; upd[u][2] = p2 * inv; upd[u][3] = p3 * inv;
    }
  }
  __syncthreads();
  if (wv < 4) {
    float v[8];
    int b0 = wv * 512 + lane * 8;
#pragma unroll
    for (int q = 0; q < 8; q++) v[q] = Vs[b0 + q];
#pragma unroll
    for (int q = 1; q < 8; q++) v[q] += v[q - 1];
    float x = v[7];
    for (int off = 1; off < 64; off <<= 1) {
      float y = __shfl_up(x, off);
      if (lane >= off) x += y;
    }
    float excl = x - v[7];
#pragma unroll
    for (int q = 0; q < 8; q++) Vs[b0 + q] = v[q] + excl;
  }
  __syncthreads();
  if (tid < 4 * U) { int u = tid >> 2, d = tid & 3; Vs[d * 512 + mt[u]] = upd[u][d]; }
  __syncthreads();
#pragma unroll
  for (int i = 0; i < 4; i++) Ctx[base + i * 512 + tid] = Vs[i * 512 + tid];
}

// ---------------- A4: out-projection
__global__ __launch_bounds__(256) void oproj_k(const float* __restrict__ Ctx,
    const float* __restrict__ Wo, const float* __restrict__ bo, float* __restrict__ Y) {
  __shared__ float cs[32 * 256];
  __shared__ float wo[32 * 33];
  __shared__ float bos[32];
  int tid = threadIdx.x;
  int a = blockIdx.x, t0 = blockIdx.y * 256;
#pragma unroll
  for (int i = 0; i < 4; i++) {
    int e = i * 256 + tid; int r = e >> 5, c = e & 31;
    wo[r * 33 + c] = Wo[e];
  }
  if (tid < 32) bos[tid] = bo[tid];
#pragma unroll
  for (int i = 0; i < 32; i++) {
    int e = i * 256 + tid; int row = e >> 8, col = e & 255;
    cs[e] = Ctx[(size_t)a * 16384 + (size_t)row * 512 + t0 + col];
  }
  __syncthreads();
  int rl = tid & 31, tw = tid >> 5;
  for (int ti = 0; ti < 32; ti++) {
    int t = ti * 8 + tw;
    float acc = bos[rl];
#pragma unroll
    for (int rp = 0; rp < 32; rp++) acc += cs[rp * 256 + t] * wo[rl * 33 + rp];
    Y[(size_t)a * 16384 + (size_t)(t0 + t) * 32 + rl] = acc;
  }
}

// ---------------- T1: transpose + relu + res1 + bn1 -> Xh fp32 + f bf16
__global__ __launch_bounds__(256) void bn1t_k(const float* __restrict__ Y,
    const float* __restrict__ x, const float* __restrict__ g1, const float* __restrict__ be1,
    const float* __restrict__ me1, const float* __restrict__ va1,
    float* __restrict__ Xh, unsigned short* __restrict__ Fb) {
  __shared__ float tl[32][33];
  int tx = threadIdx.x & 31, ty = threadIdx.x >> 5;
  int c0 = blockIdx.x * 32;
  int r0 = blockIdx.y * 32;
#pragma unroll
  for (int i = 0; i < 4; i++)
    tl[ty + i * 8][tx] = Y[(size_t)(r0 + ty + i * 8) * 16384 + c0 + tx];
  __syncthreads();
#pragma unroll
  for (int i = 0; i < 4; i++) {
    int m = c0 + ty + i * 8;
    int a = r0 + tx;
    float v = tl[tx][ty + i * 8];
    int ch = m & 31;
    size_t oi = (size_t)m * 128 + a;
    float val = fmaxf(v, 0.f) + x[oi];
    float s = g1[ch] * rsqrtf(va1[ch] + EPSF);
    float res = (val - me1[ch]) * s + be1[ch];
    Xh[oi] = res;
    Fb[oi] = f2bf(res);
  }
}

// ---------------- W fp32 -> bf16 (serial; used for W1 only in tier A)
__global__ __launch_bounds__(256) void wcvt_k(const float* __restrict__ W,
    unsigned short* __restrict__ Wb, int n4) {
  int stride = gridDim.x * 256;
  for (int idx = blockIdx.x * 256 + threadIdx.x; idx < n4; idx += stride) {
    float4 w = ((const float4*)W)[idx];
    ushort4 o;
    o.x = f2bf(w.x); o.y = f2bf(w.y); o.z = f2bf(w.z); o.w = f2bf(w.w);
    ((ushort4*)Wb)[idx] = o;
  }
}

// ---------------- All-bf16 m97-tile GEMM with split-K partials (fp16 P).
// Tail: optional grid-stride W fp32->bf16 convert (next GEMM's weights) --
// hides under other blocks' MFMA (proven net-positive, round 5).
__global__ __launch_bounds__(256, 3) void gemm_bf(
    const unsigned short* __restrict__ A, const unsigned short* __restrict__ B,
    int K, int N, int MT, int NPX, int SPLITK, h16* __restrict__ P, int M,
    const float* __restrict__ Wsrc, unsigned short* __restrict__ Wdst, int wn4) {
  __shared__ unsigned char lds[16384];  // A 8KB | B 8KB
  int tid = threadIdx.x;
  int lane = tid & 63, wv = tid >> 6;
  int wm = wv >> 1, wn = wv & 1;
  int lin = blockIdx.x;
  int xcd = lin & 7, slot = lin >> 3;
  int tilesPerSp = MT * NPX;
  int sp = slot / tilesPerSp;
  int rem = slot % tilesPerSp;
  int mt = rem % MT;
  int nt = xcd * NPX + rem / MT;
  int mtile0 = mt * 128, ntile0 = nt * 128;
  int m0 = mtile0 + wm * 64, n0 = ntile0 + wn * 64;
  int frow = lane & 15, q = lane >> 4;

  int nk = K / (32 * SPLITK);
  int kbase = sp * (K / SPLITK);

  f32x4 acc[4][4];
#pragma unroll
  for (int i = 0; i < 4; i++)
#pragma unroll
    for (int j = 0; j < 4; j++) { f32x4 z = {0.f, 0.f, 0.f, 0.f}; acc[i][j] = z; }

  for (int k = 0; k < nk; k++) {
    int ks = kbase + k * 32;
#pragma unroll
    for (int i = 0; i < 2; i++) {
      int e = i * 256 + tid;
      int row = e >> 2;
      int g = (e & 3) ^ ((row >> 1) & 3);
      async16(A + (size_t)(mtile0 + row) * K + ks + g * 8, lds + i * 4096 + wv * 1024);
    }
#pragma unroll
    for (int i = 0; i < 2; i++) {
      int e = i * 256 + tid;
      int row = e >> 2;
      int g = (e & 3) ^ ((row >> 1) & 3);
      async16(B + (size_t)(ntile0 + row) * K + ks + g * 8,
              lds + 8192 + i * 4096 + wv * 1024);
    }
    __syncthreads();
    bf16x8 af[4], bfr[4];
#pragma unroll
    for (int i = 0; i < 4; i++) {
      int row = wm * 64 + i * 16 + frow;
      af[i] = *(const bf16x8*)(lds + row * 64 + ((q ^ ((row >> 1) & 3)) << 4));
    }
#pragma unroll
    for (int j = 0; j < 4; j++) {
      int row = wn * 64 + j * 16 + frow;
      bfr[j] = *(const bf16x8*)(lds + 8192 + row * 64 + ((q ^ ((row >> 1) & 3)) << 4));
    }
#pragma unroll
    for (int i = 0; i < 4; i++)
#pragma unroll
      for (int j = 0; j < 4; j++)
        acc[i][j] = __builtin_amdgcn_mfma_f32_16x16x32_bf16(af[i], bfr[j], acc[i][j], 0, 0, 0);
    __syncthreads();
  }

  h16* pb = P + (size_t)sp * M * N;
#pragma unroll
  for (int i = 0; i < 4; i++)
#pragma unroll
    for (int j = 0; j < 4; j++) {
      int n = n0 + j * 16 + frow;
      int mb = m0 + i * 16 + (q << 2);
#pragma unroll
      for (int r = 0; r < 4; r++)
        pb[(size_t)(mb + r) * N + n] = (h16)acc[i][j][r];
    }
  // ---- overlapped next-GEMM weight convert
  if (Wsrc) {
    int gstride = gridDim.x * 256;
    for (int i = lin * 256 + tid; i < wn4; i += gstride) {
      float4 w = ((const float4*)Wsrc)[i];
      ushort4 o;
      o.x = f2bf(w.x); o.y = f2bf(w.y); o.z = f2bf(w.z); o.w = f2bf(w.w);
      ((ushort4*)Wdst)[i] = o;
    }
  }
}

// ---------------- round-5 GEMM (fp32 B), kept for small-ws fallback tiers
template <int MI, int NJ, int EPI>
__global__ __launch_bounds__(256) void gemm_ps(
    const unsigned short* __restrict__ A, const float* __restrict__ Bw,
    const float* __restrict__ bias, int K, int N, int MT, int NPX, int SPLITK,
    h16* __restrict__ Pout, int M,
    unsigned short* __restrict__ Hout, const float* __restrict__ res2,
    const float* __restrict__ g2, const float* __restrict__ be2,
    const float* __restrict__ me2, const float* __restrict__ va2,
    float* __restrict__ Out) {
  constexpr int BM = MI * 32;
  constexpr int BN = NJ * 32;
  constexpr int ABYTES = BM * 32 * 2;
  constexpr int BBYTES = BN * 32 * 4;
  constexpr int SA = ABYTES / 4096;
  constexpr int SB = BBYTES / 4096;
  __shared__ unsigned char lds[ABYTES + BBYTES];
  int tid = threadIdx.x;
  int lane = tid & 63, wv = tid >> 6;
  int wm = wv >> 1, wn = wv & 1;
  int lin = blockIdx.x;
  int xcd = lin & 7, slot = lin >> 3;
  int tilesPerSp = MT * NPX;
  int sp = slot / tilesPerSp;
  int rem = slot % tilesPerSp;
  int mt = rem % MT;
  int nt = xcd * NPX + rem / MT;
  int m0 = mt * BM + wm * (BM / 2);
  int n0 = nt * BN + wn * (BN / 2);
  int frow = lane & 15, q = lane >> 4;
  int nk = K / (32 * SPLITK);
  int kbase = sp * (K / SPLITK);
  f32x4 acc[MI][NJ];
#pragma unroll
  for (int i = 0; i < MI; i++)
#pragma unroll
    for (int j = 0; j < NJ; j++) { f32x4 z = {0.f, 0.f, 0.f, 0.f}; acc[i][j] = z; }
  int mtile0 = mt * BM, ntile0 = nt * BN;
  for (int k = 0; k < nk; k++) {
    int ks = kbase + k * 32;
#pragma unroll
    for (int i = 0; i < SA; i++) {
      int e = i * 256 + tid;
      int row = e >> 2;
      int g = (e & 3) ^ ((row >> 1) & 3);
      async16(A + (size_t)(mtile0 + row) * K + ks + g * 8, lds + i * 4096 + wv * 1024);
    }
#pragma unroll
    for (int i = 0; i < SB; i++) {
      int e = i * 256 + tid;
      int row = e >> 3;
      int g = (e & 7) ^ (row & 7);
      async16(Bw + (size_t)(ntile0 + row) * K + ks + g * 4,
              lds + ABYTES + i * 4096 + wv * 1024);
    }
    __syncthreads();
    bf16x8 af[MI];
    bf16x8 bfr[NJ];
#pragma unroll
    for (int i = 0; i < MI; i++) {
      int row = wm * (BM / 2) + i * 16 + frow;
      af[i] = *(const bf16x8*)(lds + row * 64 + ((q ^ ((row >> 1) & 3)) << 4));
    }
#pragma unroll
    for (int j = 0; j < NJ; j++) {
      int row = wn * (BN / 2) + j * 16 + frow;
      const unsigned char* rb = lds + ABYTES + row * 128;
      int sw = row & 7;
      float4 w0 = *(const float4*)(rb + (((2 * q + 0) ^ sw) << 4));
      float4 w1 = *(const float4*)(rb + (((2 * q + 1) ^ sw) << 4));
      union { u16x8 u; bf16x8 b; } cv;
      cv.u[0] = f2bf_fast(w0.x); cv.u[1] = f2bf_fast(w0.y);
      cv.u[2] = f2bf_fast(w0.z); cv.u[3] = f2bf_fast(w0.w);
      cv.u[4] = f2bf_fast(w1.x); cv.u[5] = f2bf_fast(w1.y);
      cv.u[6] = f2bf_fast(w1.z); cv.u[7] = f2bf_fast(w1.w);
      bfr[j] = cv.b;
    }
#pragma unroll
    for (int i = 0; i < MI; i++)
#pragma unroll
      for (int j = 0; j < NJ; j++)
        acc[i][j] = __builtin_amdgcn_mfma_f32_16x16x32_bf16(af[i], bfr[j], acc[i][j], 0, 0, 0);
    __syncthreads();
  }
#pragma unroll
  for (int i = 0; i < MI; i++)
#pragma unroll
    for (int j = 0; j < NJ; j++) {
      int n = n0 + j * 16 + frow;
      int mb = m0 + i * 16 + (q << 2);
      if constexpr (EPI == 2) {
        h16* pb = Pout + (size_t)sp * M * N;
#pragma unroll
        for (int r = 0; r < 4; r++)
          pb[(size_t)(mb + r) * N + n] = (h16)acc[i][j][r];
      } else if constexpr (EPI == 0) {
        float bb = bias[n];
#pragma unroll
        for (int r = 0; r < 4; r++) {
          float v = fmaxf(acc[i][j][r] + bb, 0.f);
          Hout[(size_t)(mb + r) * N + n] = f2bf(v);
        }
      } else {
        float bb = bias[n];
        int ch = n >> 7;
        float s = g2[ch] * rsqrtf(va2[ch] + EPSF);
        float mu = me2[ch], bt = be2[ch];
#pragma unroll
        for (int r = 0; r < 4; r++) {
          float v = fmaxf(acc[i][j][r] + bb, 0.f);
          size_t oi = (size_t)(mb + r) * N + n;
          v += res2[oi];
          Out[oi] = (v - mu) * s + bt;
        }
      }
    }
}

// ---------------- split-K reduce over fp16 partials, 8 outputs/thread.
// EPI 0: bf16(relu(sum+bias)) -> H.  EPI 1: bn2(relu(sum+bias)+Xh) -> Out.
template <int EPI>
__global__ __launch_bounds__(256) void redh_k(const h16* __restrict__ P, int SP,
    const float* __restrict__ bias, const float* __restrict__ Xh,
    const float* __restrict__ g2, const float* __restrict__ be2,
    const float* __restrict__ me2, const float* __restrict__ va2,
    unsigned short* __restrict__ H, float* __restrict__ Out, int N, int MN) {
  int idx = blockIdx.x * 256 + threadIdx.x;
  const h16x8* p = (const h16x8*)P;
  int mn8 = MN >> 3;
  h16x8 v0 = p[idx];
  float s[8];
#pragma unroll
  for (int e = 0; e < 8; e++) s[e] = (float)v0[e];
  for (int sp = 1; sp < SP; sp++) {
    h16x8 t = p[idx + (size_t)sp * mn8];
#pragma unroll
    for (int e = 0; e < 8; e++) s[e] += (float)t[e];
  }
  size_t off = (size_t)idx * 8;
  int n = (int)(off & (size_t)(N - 1));
  float4 b0 = *(const float4*)(bias + n);
  float4 b1 = *(const float4*)(bias + n + 4);
  float bb[8] = {b0.x, b0.y, b0.z, b0.w, b1.x, b1.y, b1.z, b1.w};
  if constexpr (EPI == 0) {
    u16x8 o;
#pragma unroll
    for (int e = 0; e < 8; e++) o[e] = f2bf(fmaxf(s[e] + bb[e], 0.f));
    *(u16x8*)(H + off) = o;
  } else {
    int ch = n >> 7;
    float sc = g2[ch] * rsqrtf(va2[ch] + EPSF);
    float mu = me2[ch], bt = be2[ch];
    float4 x0 = *(const float4*)(Xh + off);
    float4 x1 = *(const float4*)(Xh + off + 4);
    float xx[8] = {x0.x, x0.y, x0.z, x0.w, x1.x, x1.y, x1.z, x1.w};
    float oo[8];
#pragma unroll
    for (int e = 0; e < 8; e++)
      oo[e] = (fmaxf(s[e] + bb[e], 0.f) + xx[e] - mu) * sc + bt;
    float4 o0 = {oo[0], oo[1], oo[2], oo[3]};
    float4 o1 = {oo[4], oo[5], oo[6], oo[7]};
    *(float4*)(Out + off) = o0;
    *(float4*)(Out + off + 4) = o1;
  }
}

extern "C" void kernel_launch(void* const* d_in, const int* in_sizes, int n_in,
                              void* d_out, int out_size, void* d_ws, size_t ws_size,
                              hipStream_t stream) {
  const float* x  = (const float*)d_in[0];
  const float* Wq = (const float*)d_in[1];  const float* bq = (const float*)d_in[2];
  const float* Wk = (const float*)d_in[3];  const float* bk = (const float*)d_in[4];
  const float* Wv = (const float*)d_in[5];  const float* bv = (const float*)d_in[6];
  const float* Wo = (const float*)d_in[7];  const float* bo = (const float*)d_in[8];
  const float* g1 = (const float*)d_in[9];  const float* be1 = (const float*)d_in[10];
  const float* me1 = (const float*)d_in[11]; const float* va1 = (const float*)d_in[12];
  const float* W1 = (const float*)d_in[13]; const float* b1 = (const float*)d_in[14];
  const float* W2 = (const float*)d_in[15]; const float* b2 = (const float*)d_in[16];
  const float* g2 = (const float*)d_in[17]; const float* be2 = (const float*)d_in[18];
  const float* me2 = (const float*)d_in[19]; const float* va2 = (const float*)d_in[20];
  const int* idxs = (const int*)d_in[21];
  int U = in_sizes[21] / 512;
  float* out = (float*)d_out;

  char* ws = (char*)d_ws;
  float* QC = (float*)(ws);                    // 8 MB: Q, then Ctx
  float* Kb = (float*)(ws + (8u << 20));       // 8 MB: K, then h bf16
  float* Vb = (float*)(ws + (16u << 20));      // 8 MB: V, then f bf16
  float* YT = (float*)(ws + (24u << 20));      // 8 MB: xT, then Y
  float* Xh = (float*)(ws + (32u << 20));      // 8 MB: res2 fp32
  unsigned short* Fb = (unsigned short*)Vb;
  unsigned short* Hb = (unsigned short*)Kb;
  // Tier A (ws >= 240 MB): Wb1 @48 (67 MB), Wb2 @120 (67 MB), P fp16 @192 (33.6 MB)
  unsigned short* Wb1 = (unsigned short*)(ws + (48u << 20));
  unsigned short* Wb2 = (unsigned short*)(ws + (120u << 20));
  h16* PA = (h16*)(ws + (192u << 20));
  // Tier B (ws >= 112 MB): fp16 partials in round-5 layout
  h16* P1 = (h16*)(ws + (48u << 20));
  h16* P2 = (h16*)(ws + (80u << 20));
  bool tierA = ws_size >= (size_t)240 * (1u << 20);
  bool tierB = !tierA && ws_size >= (size_t)112 * (1u << 20);

  const int WN4 = (8192 * 4096) / 4;  // float4 count of each weight matrix

  dim3 b256(256);
  transpose_k<<<dim3(4, 512), b256, 0, stream>>>(x, YT, 16384, 128);
  qkv_k<<<dim3(128, 2), b256, 0, stream>>>(YT, Wq, bq, Wk, bk, Wv, bv, QC, Kb, Vb);
  topattn_k<<<dim3(1024), dim3(512), 0, stream>>>(QC, Kb, Vb, idxs, QC, U);
  oproj_k<<<dim3(128, 2), b256, 0, stream>>>(QC, Wo, bo, YT);
  bn1t_k<<<dim3(512, 4), b256, 0, stream>>>(YT, x, g1, be1, me1, va1, Xh, Fb);

  if (tierA) {
    // W1 convert: serial (proven 32 us; fusing into topattn costs more, round 5)
    wcvt_k<<<dim3(2048), b256, 0, stream>>>(W1, Wb1, WN4);
    // GEMM1 (+ overlapped W2 convert tail -- proven net win, round 5)
    gemm_bf<<<dim3(1024), b256, 0, stream>>>(Fb, Wb1, 4096, 8192, 4, 8, 4, PA, 512,
                                             W2, Wb2, WN4);
    redh_k<0><<<dim3(2048), b256, 0, stream>>>(PA, 4, b1, nullptr, nullptr, nullptr,
                                               nullptr, nullptr, Hb, nullptr, 8192,
                                               512 * 8192);
    gemm_bf<<<dim3(1024), b256, 0, stream>>>(Hb, Wb2, 8192, 4096, 4, 4, 8, PA, 512,
                                             nullptr, nullptr, 0);
    redh_k<1><<<dim3(1024), b256, 0, stream>>>(PA, 8, b2, Xh, g2, be2, me2, va2,
                                               nullptr, out, 4096, 512 * 4096);
  } else if (tierB) {
    gemm_ps<4, 2, 2><<<dim3(1024), b256, 0, stream>>>(
        Fb, W1, nullptr, 4096, 8192, 4, 16, 2, P1, 512,
        nullptr, nullptr, nullptr, nullptr, nullptr, nullptr, nullptr);
    redh_k<0><<<dim3(2048), b256, 0, stream>>>(P1, 2, b1, nullptr, nullptr, nullptr,
                                               nullptr, nullptr, Hb, nullptr, 8192,
                                               512 * 8192);
    gemm_ps<4, 2, 2><<<dim3(1024), b256, 0, stream>>>(
        Hb, W2, nullptr, 8192, 4096, 4, 8, 4, P2, 512,
        nullptr, nullptr, nullptr, nullptr, nullptr, nullptr, nullptr);
    redh_k<1><<<dim3(1024), b256, 0, stream>>>(P2, 4, b2, Xh, g2, be2, me2, va2,
                                               nullptr, out, 4096, 512 * 4096);
  } else {
    gemm_ps<4, 2, 0><<<dim3(512), b256, 0, stream>>>(
        Fb, W1, b1, 4096, 8192, 4, 16, 1, nullptr, 512,
        Hb, nullptr, nullptr, nullptr, nullptr, nullptr, nullptr);
    gemm_ps<4, 2, 1><<<dim3(256), b256, 0, stream>>>(
        Hb, W2, b2, 8192, 4096, 4, 8, 1, nullptr, 512,
        nullptr, Xh, g2, be2, me2, va2, out);
  }
}

// Round 7
// 525.807 us; speedup vs baseline: 1.0605x; 1.0605x over previous
//
#include <hip/hip_runtime.h>
#include <stdint.h>

#define EPSF 1e-5f
#define NEG_INF (-1e30f)

typedef float f32x4 __attribute__((ext_vector_type(4)));
typedef __bf16 bf16x8 __attribute__((ext_vector_type(8)));
typedef unsigned short u16x8 __attribute__((ext_vector_type(8)));
typedef _Float16 h16;
typedef _Float16 h16x8 __attribute__((ext_vector_type(8)));

typedef __attribute__((address_space(3))) unsigned char* as3_ptr;
typedef const __attribute__((address_space(1))) unsigned char* as1_ptr;

__device__ __forceinline__ void async16(const void* g, void* l) {
  __builtin_amdgcn_global_load_lds((as1_ptr)g, (as3_ptr)l, 16, 0, 0);
}

__device__ __forceinline__ unsigned short f2bf(float f) {
  union { float f; unsigned int u; } v; v.f = f;
  unsigned int r = v.u + 0x7FFFu + ((v.u >> 16) & 1u);
  return (unsigned short)(r >> 16);
}
__device__ __forceinline__ unsigned short f2bf_fast(float f) {
  union { float f; unsigned int u; } v; v.f = f;
  return (unsigned short)((v.u + 0x8000u) >> 16);
}

// ---------------- T0: generic 32x32 transpose
__global__ __launch_bounds__(256) void transpose_k(const float* __restrict__ src,
                                                   float* __restrict__ dst, int R, int C) {
  __shared__ float tl[32][33];
  int tx = threadIdx.x & 31, ty = threadIdx.x >> 5;
  int c0 = blockIdx.x * 32, r0 = blockIdx.y * 32;
#pragma unroll
  for (int i = 0; i < 4; i++)
    tl[ty + i * 8][tx] = src[(size_t)(r0 + ty + i * 8) * C + c0 + tx];
  __syncthreads();
#pragma unroll
  for (int i = 0; i < 4; i++)
    dst[(size_t)(c0 + ty + i * 8) * R + r0 + tx] = tl[tx][ty + i * 8];
}

// ---------------- A1: QKV projection (4 blocks/CU: one 64-token chunk/block)
__global__ __launch_bounds__(256) void qkv_k(const float* __restrict__ xT,
    const float* __restrict__ Wq, const float* __restrict__ bq,
    const float* __restrict__ Wk, const float* __restrict__ bk,
    const float* __restrict__ Wv, const float* __restrict__ bv,
    float* __restrict__ Q, float* __restrict__ Kq, float* __restrict__ Vq) {
  __shared__ float xs[64 * 33];
  __shared__ float wq[32 * 33], wk[32 * 33], wvs[32 * 33];
  __shared__ float bqs[32], bks[32], bvs[32];
  int tid = threadIdx.x;
  int a = blockIdx.x;
  int tbase = blockIdx.y * 64;
#pragma unroll
  for (int i = 0; i < 4; i++) {
    int e = i * 256 + tid; int r = e >> 5, c = e & 31;
    wq[r * 33 + c] = Wq[e]; wk[r * 33 + c] = Wk[e]; wvs[r * 33 + c] = Wv[e];
  }
  if (tid < 32) { bqs[tid] = bq[tid]; bks[tid] = bk[tid]; bvs[tid] = bv[tid]; }
#pragma unroll
  for (int i = 0; i < 8; i++) {
    int e = i * 256 + tid; int r = e >> 5, c = e & 31;
    xs[r * 33 + c] = xT[(size_t)a * 16384 + (size_t)tbase * 32 + e];
  }
  __syncthreads();
  int tl = tid & 63, rg = tid >> 6;
  float qa[8], ka[8], va[8];
#pragma unroll
  for (int r8 = 0; r8 < 8; r8++) {
    int r = rg * 8 + r8; qa[r8] = bqs[r]; ka[r8] = bks[r]; va[r8] = bvs[r];
  }
  for (int c = 0; c < 32; c++) {
    float xv = xs[tl * 33 + c];
#pragma unroll
    for (int r8 = 0; r8 < 8; r8++) {
      int r = rg * 8 + r8;
      qa[r8] += xv * wq[r * 33 + c];
      ka[r8] += xv * wk[r * 33 + c];
      va[r8] += xv * wvs[r * 33 + c];
    }
  }
  int t = tbase + tl;
#pragma unroll
  for (int r8 = 0; r8 < 8; r8++) {
    int r = rg * 8 + r8;
    size_t o = (size_t)a * 16384 + (size_t)r * 512 + t;
    Q[o] = qa[r8]; Kq[o] = ka[r8]; Vq[o] = va[r8];
  }
}

// ---------------- A2+A3 merged: rank-based top-U + attention core.
__global__ __launch_bounds__(512) void topattn_k(const float* __restrict__ Q,
    const float* __restrict__ Kq, const float* __restrict__ Vq,
    const int* __restrict__ idxs, float* __restrict__ Ctx, int U) {
  __shared__ float Ks[2048];
  __shared__ float Vs[2048];
  __shared__ float Ml[512];
  __shared__ int mt[64];
  __shared__ float Qr[64][4];
  __shared__ float upd[64][4];
  int bh = blockIdx.x;
  int tid = threadIdx.x, lane = tid & 63, wv = tid >> 6;
  size_t base = (size_t)bh * 2048;
#pragma unroll
  for (int i = 0; i < 4; i++) {
    Ks[i * 512 + tid] = Kq[base + i * 512 + tid];
    Vs[i * 512 + tid] = Vq[base + i * 512 + tid];
  }
  float q0 = Q[base + tid], q1 = Q[base + 512 + tid];
  float q2 = Q[base + 1024 + tid], q3 = Q[base + 1536 + tid];
  __syncthreads();
  float mx = NEG_INF, sm = 0.f;
  for (int u = 0; u < U; u++) {
    int it = idxs[tid * U + u];
    it = min(max(it, 0), 511);
    float s = q0 * Ks[it] + q1 * Ks[512 + it] + q2 * Ks[1024 + it] + q3 * Ks[1536 + it];
    mx = fmaxf(mx, s); sm += s;
  }
  Ml[tid] = mx - sm * (1.f / 512.f);
  __syncthreads();
  float mi = Ml[tid];
  int rank = 0;
  for (int j0 = 0; j0 < 512; j0 += 4) {
    float4 m4 = *(const float4*)(Ml + j0);
    rank += (m4.x > mi) || (m4.x == mi && (j0 + 0) < tid);
    rank += (m4.y > mi) || (m4.y == mi && (j0 + 1) < tid);
    rank += (m4.z > mi) || (m4.z == mi && (j0 + 2) < tid);
    rank += (m4.w > mi) || (m4.w == mi && (j0 + 3) < tid);
  }
  if (rank < U) mt[rank] = tid;
  __syncthreads();
  if (tid < 4 * U) { int u = tid >> 2, d = tid & 3; Qr[u][d] = Q[base + d * 512 + mt[u]]; }
  __syncthreads();
  for (int u = wv; u < U; u += 8) {
    int mrow = mt[u];
    float p0q = Qr[u][0], p1q = Qr[u][1], p2q = Qr[u][2], p3q = Qr[u][3];
    float sv[8]; float lmax = NEG_INF;
#pragma unroll
    for (int jj = 0; jj < 8; jj++) {
      int k = jj * 64 + lane;
      float s = NEG_INF;
      if (k <= mrow)
        s = 0.5f * (p0q * Ks[k] + p1q * Ks[512 + k] + p2q * Ks[1024 + k] + p3q * Ks[1536 + k]);
      sv[jj] = s; lmax = fmaxf(lmax, s);
    }
#pragma unroll
    for (int off = 32; off; off >>= 1) lmax = fmaxf(lmax, __shfl_xor(lmax, off));
    float ls = 0.f, p0 = 0.f, p1 = 0.f, p2 = 0.f, p3 = 0.f;
#pragma unroll
    for (int jj = 0; jj < 8; jj++) {
      int k = jj * 64 + lane;
      if (k <= mrow) {
        float p = __expf(sv[jj] - lmax);
        ls += p; p0 += p * Vs[k]; p1 += p * Vs[512 + k];
        p2 += p * Vs[1024 + k]; p3 += p * Vs[1536 + k];
      }
    }
#pragma unroll
    for (int off = 32; off; off >>= 1) {
      ls += __shfl_xor(ls, off); p0 += __shfl_xor(p0, off); p1 += __shfl_xor(p1, off);
      p2 += __shfl_xor(p2, off); p3 += __shfl_xor(p3, off);
    }
    if (lane == 0) {
      float inv = 1.f / ls;
      upd[u][0] = p0 * inv; upd[u][1] = p1 * inv; upd[u][2] = p2 * inv; upd[u][3] = p3 * inv;
    }
  }
  __syncthreads();
  if (wv < 4) {
    float v[8];
    int b0 = wv * 512 + lane * 8;
#pragma unroll
    for (int q = 0; q < 8; q++) v[q] = Vs[b0 + q];
#pragma unroll
    for (int q = 1; q < 8; q++) v[q] += v[q - 1];
    float x = v[7];
    for (int off = 1; off < 64; off <<= 1) {
      float y = __shfl_up(x, off);
      if (lane >= off) x += y;
    }
    float excl = x - v[7];
#pragma unroll
    for (int q = 0; q < 8; q++) Vs[b0 + q] = v[q] + excl;
  }
  __syncthreads();
  if (tid < 4 * U) { int u = tid >> 2, d = tid & 3; Vs[d * 512 + mt[u]] = upd[u][d]; }
  __syncthreads();
#pragma unroll
  for (int i = 0; i < 4; i++) Ctx[base + i * 512 + tid] = Vs[i * 512 + tid];
}

// ---------------- A4: out-projection (4 blocks/CU: 64-col tiles)
__global__ __launch_bounds__(256) void oproj_k(const float* __restrict__ Ctx,
    const float* __restrict__ Wo, const float* __restrict__ bo, float* __restrict__ Y) {
  __shared__ float cs[32 * 64];
  __shared__ float wo[32 * 33];
  __shared__ float bos[32];
  int tid = threadIdx.x;
  int a = blockIdx.x, t0 = blockIdx.y * 64;
#pragma unroll
  for (int i = 0; i < 4; i++) {
    int e = i * 256 + tid; int r = e >> 5, c = e & 31;
    wo[r * 33 + c] = Wo[e];
  }
  if (tid < 32) bos[tid] = bo[tid];
#pragma unroll
  for (int i = 0; i < 8; i++) {
    int e = i * 256 + tid; int row = e >> 6, col = e & 63;
    cs[e] = Ctx[(size_t)a * 16384 + (size_t)row * 512 + t0 + col];
  }
  __syncthreads();
  int rl = tid & 31, tw = tid >> 5;
#pragma unroll
  for (int ti = 0; ti < 8; ti++) {
    int t = ti * 8 + tw;
    float acc = bos[rl];
#pragma unroll
    for (int rp = 0; rp < 32; rp++) acc += cs[rp * 64 + t] * wo[rl * 33 + rp];
    Y[(size_t)a * 16384 + (size_t)(t0 + t) * 32 + rl] = acc;
  }
}

// ---------------- T1: transpose + relu + res1 + bn1 -> Xh fp32 + f bf16
__global__ __launch_bounds__(256) void bn1t_k(const float* __restrict__ Y,
    const float* __restrict__ x, const float* __restrict__ g1, const float* __restrict__ be1,
    const float* __restrict__ me1, const float* __restrict__ va1,
    float* __restrict__ Xh, unsigned short* __restrict__ Fb) {
  __shared__ float tl[32][33];
  int tx = threadIdx.x & 31, ty = threadIdx.x >> 5;
  int c0 = blockIdx.x * 32;
  int r0 = blockIdx.y * 32;
#pragma unroll
  for (int i = 0; i < 4; i++)
    tl[ty + i * 8][tx] = Y[(size_t)(r0 + ty + i * 8) * 16384 + c0 + tx];
  __syncthreads();
#pragma unroll
  for (int i = 0; i < 4; i++) {
    int m = c0 + ty + i * 8;
    int a = r0 + tx;
    float v = tl[tx][ty + i * 8];
    int ch = m & 31;
    size_t oi = (size_t)m * 128 + a;
    float val = fmaxf(v, 0.f) + x[oi];
    float s = g1[ch] * rsqrtf(va1[ch] + EPSF);
    float res = (val - me1[ch]) * s + be1[ch];
    Xh[oi] = res;
    Fb[oi] = f2bf(res);
  }
}

// ---------------- W fp32 -> bf16 (serial; proven optimal placement, r4-r6)
__global__ __launch_bounds__(256) void wcvt_k(const float* __restrict__ W,
    unsigned short* __restrict__ Wb, int n4) {
  int stride = gridDim.x * 256;
  for (int idx = blockIdx.x * 256 + threadIdx.x; idx < n4; idx += stride) {
    float4 w = ((const float4*)W)[idx];
    ushort4 o;
    o.x = f2bf(w.x); o.y = f2bf(w.y); o.z = f2bf(w.z); o.w = f2bf(w.w);
    ((ushort4*)Wb)[idx] = o;
  }
}

// ---------------- All-bf16 m97-tile GEMM with split-K partials (fp16 P).
__global__ __launch_bounds__(256, 3) void gemm_bf(
    const unsigned short* __restrict__ A, const unsigned short* __restrict__ B,
    int K, int N, int MT, int NPX, int SPLITK, h16* __restrict__ P, int M) {
  __shared__ unsigned char lds[16384];  // A 8KB | B 8KB
  int tid = threadIdx.x;
  int lane = tid & 63, wv = tid >> 6;
  int wm = wv >> 1, wn = wv & 1;
  int lin = blockIdx.x;
  int xcd = lin & 7, slot = lin >> 3;
  int tilesPerSp = MT * NPX;
  int sp = slot / tilesPerSp;
  int rem = slot % tilesPerSp;
  int mt = rem % MT;
  int nt = xcd * NPX + rem / MT;
  int mtile0 = mt * 128, ntile0 = nt * 128;
  int m0 = mtile0 + wm * 64, n0 = ntile0 + wn * 64;
  int frow = lane & 15, q = lane >> 4;

  int nk = K / (32 * SPLITK);
  int kbase = sp * (K / SPLITK);

  f32x4 acc[4][4];
#pragma unroll
  for (int i = 0; i < 4; i++)
#pragma unroll
    for (int j = 0; j < 4; j++) { f32x4 z = {0.f, 0.f, 0.f, 0.f}; acc[i][j] = z; }

  for (int k = 0; k < nk; k++) {
    int ks = kbase + k * 32;
#pragma unroll
    for (int i = 0; i < 2; i++) {
      int e = i * 256 + tid;
      int row = e >> 2;
      int g = (e & 3) ^ ((row >> 1) & 3);
      async16(A + (size_t)(mtile0 + row) * K + ks + g * 8, lds + i * 4096 + wv * 1024);
    }
#pragma unroll
    for (int i = 0; i < 2; i++) {
      int e = i * 256 + tid;
      int row = e >> 2;
      int g = (e & 3) ^ ((row >> 1) & 3);
      async16(B + (size_t)(ntile0 + row) * K + ks + g * 8,
              lds + 8192 + i * 4096 + wv * 1024);
    }
    __syncthreads();
    bf16x8 af[4], bfr[4];
#pragma unroll
    for (int i = 0; i < 4; i++) {
      int row = wm * 64 + i * 16 + frow;
      af[i] = *(const bf16x8*)(lds + row * 64 + ((q ^ ((row >> 1) & 3)) << 4));
    }
#pragma unroll
    for (int j = 0; j < 4; j++) {
      int row = wn * 64 + j * 16 + frow;
      bfr[j] = *(const bf16x8*)(lds + 8192 + row * 64 + ((q ^ ((row >> 1) & 3)) << 4));
    }
#pragma unroll
    for (int i = 0; i < 4; i++)
#pragma unroll
      for (int j = 0; j < 4; j++)
        acc[i][j] = __builtin_amdgcn_mfma_f32_16x16x32_bf16(af[i], bfr[j], acc[i][j], 0, 0, 0);
    __syncthreads();
  }

  h16* pb = P + (size_t)sp * M * N;
#pragma unroll
  for (int i = 0; i < 4; i++)
#pragma unroll
    for (int j = 0; j < 4; j++) {
      int n = n0 + j * 16 + frow;
      int mb = m0 + i * 16 + (q << 2);
#pragma unroll
      for (int r = 0; r < 4; r++)
        pb[(size_t)(mb + r) * N + n] = (h16)acc[i][j][r];
    }
}

// ---------------- round-5 GEMM (fp32 B), kept for small-ws fallback tiers
template <int MI, int NJ, int EPI>
__global__ __launch_bounds__(256) void gemm_ps(
    const unsigned short* __restrict__ A, const float* __restrict__ Bw,
    const float* __restrict__ bias, int K, int N, int MT, int NPX, int SPLITK,
    h16* __restrict__ Pout, int M,
    unsigned short* __restrict__ Hout, const float* __restrict__ res2,
    const float* __restrict__ g2, const float* __restrict__ be2,
    const float* __restrict__ me2, const float* __restrict__ va2,
    float* __restrict__ Out) {
  constexpr int BM = MI * 32;
  constexpr int BN = NJ * 32;
  constexpr int ABYTES = BM * 32 * 2;
  constexpr int BBYTES = BN * 32 * 4;
  constexpr int SA = ABYTES / 4096;
  constexpr int SB = BBYTES / 4096;
  __shared__ unsigned char lds[ABYTES + BBYTES];
  int tid = threadIdx.x;
  int lane = tid & 63, wv = tid >> 6;
  int wm = wv >> 1, wn = wv & 1;
  int lin = blockIdx.x;
  int xcd = lin & 7, slot = lin >> 3;
  int tilesPerSp = MT * NPX;
  int sp = slot / tilesPerSp;
  int rem = slot % tilesPerSp;
  int mt = rem % MT;
  int nt = xcd * NPX + rem / MT;
  int m0 = mt * BM + wm * (BM / 2);
  int n0 = nt * BN + wn * (BN / 2);
  int frow = lane & 15, q = lane >> 4;
  int nk = K / (32 * SPLITK);
  int kbase = sp * (K / SPLITK);
  f32x4 acc[MI][NJ];
#pragma unroll
  for (int i = 0; i < MI; i++)
#pragma unroll
    for (int j = 0; j < NJ; j++) { f32x4 z = {0.f, 0.f, 0.f, 0.f}; acc[i][j] = z; }
  int mtile0 = mt * BM, ntile0 = nt * BN;
  for (int k = 0; k < nk; k++) {
    int ks = kbase + k * 32;
#pragma unroll
    for (int i = 0; i < SA; i++) {
      int e = i * 256 + tid;
      int row = e >> 2;
      int g = (e & 3) ^ ((row >> 1) & 3);
      async16(A + (size_t)(mtile0 + row) * K + ks + g * 8, lds + i * 4096 + wv * 1024);
    }
#pragma unroll
    for (int i = 0; i < SB; i++) {
      int e = i * 256 + tid;
      int row = e >> 3;
      int g = (e & 7) ^ (row & 7);
      async16(Bw + (size_t)(ntile0 + row) * K + ks + g * 4,
              lds + ABYTES + i * 4096 + wv * 1024);
    }
    __syncthreads();
    bf16x8 af[MI];
    bf16x8 bfr[NJ];
#pragma unroll
    for (int i = 0; i < MI; i++) {
      int row = wm * (BM / 2) + i * 16 + frow;
      af[i] = *(const bf16x8*)(lds + row * 64 + ((q ^ ((row >> 1) & 3)) << 4));
    }
#pragma unroll
    for (int j = 0; j < NJ; j++) {
      int row = wn * (BN / 2) + j * 16 + frow;
      const unsigned char* rb = lds + ABYTES + row * 128;
      int sw = row & 7;
      float4 w0 = *(const float4*)(rb + (((2 * q + 0) ^ sw) << 4));
      float4 w1 = *(const float4*)(rb + (((2 * q + 1) ^ sw) << 4));
      union { u16x8 u; bf16x8 b; } cv;
      cv.u[0] = f2bf_fast(w0.x); cv.u[1] = f2bf_fast(w0.y);
      cv.u[2] = f2bf_fast(w0.z); cv.u[3] = f2bf_fast(w0.w);
      cv.u[4] = f2bf_fast(w1.x); cv.u[5] = f2bf_fast(w1.y);
      cv.u[6] = f2bf_fast(w1.z); cv.u[7] = f2bf_fast(w1.w);
      bfr[j] = cv.b;
    }
#pragma unroll
    for (int i = 0; i < MI; i++)
#pragma unroll
      for (int j = 0; j < NJ; j++)
        acc[i][j] = __builtin_amdgcn_mfma_f32_16x16x32_bf16(af[i], bfr[j], acc[i][j], 0, 0, 0);
    __syncthreads();
  }
#pragma unroll
  for (int i = 0; i < MI; i++)
#pragma unroll
    for (int j = 0; j < NJ; j++) {
      int n = n0 + j * 16 + frow;
      int mb = m0 + i * 16 + (q << 2);
      if constexpr (EPI == 2) {
        h16* pb = Pout + (size_t)sp * M * N;
#pragma unroll
        for (int r = 0; r < 4; r++)
          pb[(size_t)(mb + r) * N + n] = (h16)acc[i][j][r];
      } else if constexpr (EPI == 0) {
        float bb = bias[n];
#pragma unroll
        for (int r = 0; r < 4; r++) {
          float v = fmaxf(acc[i][j][r] + bb, 0.f);
          Hout[(size_t)(mb + r) * N + n] = f2bf(v);
        }
      } else {
        float bb = bias[n];
        int ch = n >> 7;
        float s = g2[ch] * rsqrtf(va2[ch] + EPSF);
        float mu = me2[ch], bt = be2[ch];
#pragma unroll
        for (int r = 0; r < 4; r++) {
          float v = fmaxf(acc[i][j][r] + bb, 0.f);
          size_t oi = (size_t)(mb + r) * N + n;
          v += res2[oi];
          Out[oi] = (v - mu) * s + bt;
        }
      }
    }
}

// ---------------- split-K reduce over fp16 partials, 8 outputs/thread.
template <int EPI>
__global__ __launch_bounds__(256) void redh_k(const h16* __restrict__ P, int SP,
    const float* __restrict__ bias, const float* __restrict__ Xh,
    const float* __restrict__ g2, const float* __restrict__ be2,
    const float* __restrict__ me2, const float* __restrict__ va2,
    unsigned short* __restrict__ H, float* __restrict__ Out, int N, int MN) {
  int idx = blockIdx.x * 256 + threadIdx.x;
  const h16x8* p = (const h16x8*)P;
  int mn8 = MN >> 3;
  h16x8 v0 = p[idx];
  float s[8];
#pragma unroll
  for (int e = 0; e < 8; e++) s[e] = (float)v0[e];
  for (int sp = 1; sp < SP; sp++) {
    h16x8 t = p[idx + (size_t)sp * mn8];
#pragma unroll
    for (int e = 0; e < 8; e++) s[e] += (float)t[e];
  }
  size_t off = (size_t)idx * 8;
  int n = (int)(off & (size_t)(N - 1));
  float4 b0 = *(const float4*)(bias + n);
  float4 b1 = *(const float4*)(bias + n + 4);
  float bb[8] = {b0.x, b0.y, b0.z, b0.w, b1.x, b1.y, b1.z, b1.w};
  if constexpr (EPI == 0) {
    u16x8 o;
#pragma unroll
    for (int e = 0; e < 8; e++) o[e] = f2bf(fmaxf(s[e] + bb[e], 0.f));
    *(u16x8*)(H + off) = o;
  } else {
    int ch = n >> 7;
    float sc = g2[ch] * rsqrtf(va2[ch] + EPSF);
    float mu = me2[ch], bt = be2[ch];
    float4 x0 = *(const float4*)(Xh + off);
    float4 x1 = *(const float4*)(Xh + off + 4);
    float xx[8] = {x0.x, x0.y, x0.z, x0.w, x1.x, x1.y, x1.z, x1.w};
    float oo[8];
#pragma unroll
    for (int e = 0; e < 8; e++)
      oo[e] = (fmaxf(s[e] + bb[e], 0.f) + xx[e] - mu) * sc + bt;
    float4 o0 = {oo[0], oo[1], oo[2], oo[3]};
    float4 o1 = {oo[4], oo[5], oo[6], oo[7]};
    *(float4*)(Out + off) = o0;
    *(float4*)(Out + off + 4) = o1;
  }
}

extern "C" void kernel_launch(void* const* d_in, const int* in_sizes, int n_in,
                              void* d_out, int out_size, void* d_ws, size_t ws_size,
                              hipStream_t stream) {
  const float* x  = (const float*)d_in[0];
  const float* Wq = (const float*)d_in[1];  const float* bq = (const float*)d_in[2];
  const float* Wk = (const float*)d_in[3];  const float* bk = (const float*)d_in[4];
  const float* Wv = (const float*)d_in[5];  const float* bv = (const float*)d_in[6];
  const float* Wo = (const float*)d_in[7];  const float* bo = (const float*)d_in[8];
  const float* g1 = (const float*)d_in[9];  const float* be1 = (const float*)d_in[10];
  const float* me1 = (const float*)d_in[11]; const float* va1 = (const float*)d_in[12];
  const float* W1 = (const float*)d_in[13]; const float* b1 = (const float*)d_in[14];
  const float* W2 = (const float*)d_in[15]; const float* b2 = (const float*)d_in[16];
  const float* g2 = (const float*)d_in[17]; const float* be2 = (const float*)d_in[18];
  const float* me2 = (const float*)d_in[19]; const float* va2 = (const float*)d_in[20];
  const int* idxs = (const int*)d_in[21];
  int U = in_sizes[21] / 512;
  float* out = (float*)d_out;

  char* ws = (char*)d_ws;
  float* QC = (float*)(ws);                    // 8 MB: Q, then Ctx
  float* Kb = (float*)(ws + (8u << 20));       // 8 MB: K, then h bf16
  float* Vb = (float*)(ws + (16u << 20));      // 8 MB: V, then f bf16
  float* YT = (float*)(ws + (24u << 20));      // 8 MB: xT, then Y
  float* Xh = (float*)(ws + (32u << 20));      // 8 MB: res2 fp32
  unsigned short* Fb = (unsigned short*)Vb;
  unsigned short* Hb = (unsigned short*)Kb;
  // Tier A (ws >= 176 MB): Wb 64 MB @48 (W1b then W2b), P fp16 (33.6 MB) @112
  unsigned short* Wb = (unsigned short*)(ws + (48u << 20));
  h16* PA = (h16*)(ws + (112u << 20));
  // Tier B (ws >= 112 MB): fp16 partials in round-5 layout
  h16* P1 = (h16*)(ws + (48u << 20));
  h16* P2 = (h16*)(ws + (80u << 20));
  bool tierA = ws_size >= (size_t)176 * (1u << 20);
  bool tierB = !tierA && ws_size >= (size_t)112 * (1u << 20);

  const int WN4 = (8192 * 4096) / 4;

  dim3 b256(256);
  transpose_k<<<dim3(4, 512), b256, 0, stream>>>(x, YT, 16384, 128);
  qkv_k<<<dim3(128, 8), b256, 0, stream>>>(YT, Wq, bq, Wk, bk, Wv, bv, QC, Kb, Vb);
  topattn_k<<<dim3(1024), dim3(512), 0, stream>>>(QC, Kb, Vb, idxs, QC, U);
  oproj_k<<<dim3(128, 8), b256, 0, stream>>>(QC, Wo, bo, YT);
  bn1t_k<<<dim3(512, 4), b256, 0, stream>>>(YT, x, g1, be1, me1, va1, Xh, Fb);

  if (tierA) {
    wcvt_k<<<dim3(2048), b256, 0, stream>>>(W1, Wb, WN4);
    gemm_bf<<<dim3(1024), b256, 0, stream>>>(Fb, Wb, 4096, 8192, 4, 8, 4, PA, 512);
    redh_k<0><<<dim3(2048), b256, 0, stream>>>(PA, 4, b1, nullptr, nullptr, nullptr,
                                               nullptr, nullptr, Hb, nullptr, 8192,
                                               512 * 8192);
    wcvt_k<<<dim3(2048), b256, 0, stream>>>(W2, Wb, WN4);
    gemm_bf<<<dim3(1024), b256, 0, stream>>>(Hb, Wb, 8192, 4096, 4, 4, 8, PA, 512);
    redh_k<1><<<dim3(1024), b256, 0, stream>>>(PA, 8, b2, Xh, g2, be2, me2, va2,
                                               nullptr, out, 4096, 512 * 4096);
  } else if (tierB) {
    gemm_ps<4, 2, 2><<<dim3(1024), b256, 0, stream>>>(
        Fb, W1, nullptr, 4096, 8192, 4, 16, 2, P1, 512,
        nullptr, nullptr, nullptr, nullptr, nullptr, nullptr, nullptr);
    redh_k<0><<<dim3(2048), b256, 0, stream>>>(P1, 2, b1, nullptr, nullptr, nullptr,
                                               nullptr, nullptr, Hb, nullptr, 8192,
                                               512 * 8192);
    gemm_ps<4, 2, 2><<<dim3(1024), b256, 0, stream>>>(
        Hb, W2, nullptr, 8192, 4096, 4, 8, 4, P2, 512,
        nullptr, nullptr, nullptr, nullptr, nullptr, nullptr, nullptr);
    redh_k<1><<<dim3(1024), b256, 0, stream>>>(P2, 4, b2, Xh, g2, be2, me2, va2,
                                               nullptr, out, 4096, 512 * 4096);
  } else {
    gemm_ps<4, 2, 0><<<dim3(512), b256, 0, stream>>>(
        Fb, W1, b1, 4096, 8192, 4, 16, 1, nullptr, 512,
        Hb, nullptr, nullptr, nullptr, nullptr, nullptr, nullptr);
    gemm_ps<4, 2, 1><<<dim3(256), b256, 0, stream>>>(
        Hb, W2, b2, 8192, 4096, 4, 8, 1, nullptr, 512,
        nullptr, Xh, g2, be2, me2, va2, out);
  }
}